// Round 1
// baseline (26299.353 us; speedup 1.0000x reference)
//
#include <hip/hip_runtime.h>

#define T_LEN 8192
#define L_CH  16
#define EW    256
#define EC    64
#define HID   512
#define H2    128
#define TAGS  64

#define NBLK_REC 16
#define THR_REC  512
#define A_WORDS  16

// ---------------------------------------------------------------- init
__global__ void k_init(float* hglob, unsigned int* flags) {
    int t = threadIdx.x;
    for (int i = t; i < 2 * HID; i += blockDim.x) hglob[i] = 0.f;
    if (t < NBLK_REC) flags[t] = 0u;
}

// ---------------------------------------------------------------- char LSTM
// grid 512, block 256. Each block: 16 words, 16 char steps.
// thread: rowg = tid>>2 (8 gate rows), wg = tid&3 (4 words)
__global__ __launch_bounds__(256) void k_char(const int* __restrict__ seq_chars,
                                              const float* __restrict__ emb_char,
                                              const float* __restrict__ Wih,
                                              const float* __restrict__ Whh,
                                              const float* __restrict__ bc,
                                              float* __restrict__ h_char) {
    __shared__ float xs[A_WORDS][76];    // padded, 16B-aligned rows
    __shared__ float hs[A_WORDS][132];
    __shared__ float cs[A_WORDS][128];
    __shared__ float gs[A_WORDS][512];

    const int tid = threadIdx.x;
    const int w0  = blockIdx.x * A_WORDS;

    for (int i = tid; i < A_WORDS * 132; i += 256) hs[i / 132][i % 132] = 0.f;
    for (int i = tid; i < A_WORDS * 128; i += 256) cs[i >> 7][i & 127] = 0.f;

    const int rowg = tid >> 2;       // 0..63
    const int wg   = tid & 3;        // 0..3
    const int r0   = rowg * 8;
    const int wb   = wg * 4;

    float bias_r[8];
#pragma unroll
    for (int r = 0; r < 8; ++r) bias_r[r] = bc[r0 + r];

    for (int l = 0; l < L_CH; ++l) {
        __syncthreads();   // prev elementwise done (h,c stable)
        {   // gather x: 16 words x 16 float4
            int w = tid >> 4, p = tid & 15;
            int ci = seq_chars[(w0 + w) * L_CH + l];
            float4 v = ((const float4*)emb_char)[ci * 16 + p];
            *(float4*)&xs[w][p * 4] = v;
        }
        __syncthreads();

        float acc[8][4];
#pragma unroll
        for (int r = 0; r < 8; ++r)
#pragma unroll
            for (int w = 0; w < 4; ++w) acc[r][w] = bias_r[r];

        // x part: K = 64
#pragma unroll 4
        for (int k4 = 0; k4 < 16; ++k4) {
            float4 wv[8];
#pragma unroll
            for (int r = 0; r < 8; ++r) wv[r] = ((const float4*)Wih)[(r0 + r) * 16 + k4];
#pragma unroll
            for (int w = 0; w < 4; ++w) {
                const float4 xv = *(const float4*)&xs[wb + w][k4 * 4];
#pragma unroll
                for (int r = 0; r < 8; ++r)
                    acc[r][w] += wv[r].x * xv.x + wv[r].y * xv.y + wv[r].z * xv.z + wv[r].w * xv.w;
            }
        }
        // h part: K = 128
#pragma unroll 2
        for (int k4 = 0; k4 < 32; ++k4) {
            float4 wv[8];
#pragma unroll
            for (int r = 0; r < 8; ++r) wv[r] = ((const float4*)Whh)[(r0 + r) * 32 + k4];
#pragma unroll
            for (int w = 0; w < 4; ++w) {
                const float4 hv = *(const float4*)&hs[wb + w][k4 * 4];
#pragma unroll
                for (int r = 0; r < 8; ++r)
                    acc[r][w] += wv[r].x * hv.x + wv[r].y * hv.y + wv[r].z * hv.z + wv[r].w * hv.w;
            }
        }
#pragma unroll
        for (int r = 0; r < 8; ++r)
#pragma unroll
            for (int w = 0; w < 4; ++w) gs[wb + w][r0 + r] = acc[r][w];
        __syncthreads();

        {   // elementwise: 16 words * 128 comps / 256 threads = 8 each
            int w = tid >> 4;
            int j0 = (tid & 15) * 8;
#pragma unroll
            for (int u = 0; u < 8; ++u) {
                int j = j0 + u;
                float gi = gs[w][j], gf = gs[w][128 + j], gg = gs[w][256 + j], go = gs[w][384 + j];
                float si = 1.f / (1.f + __expf(-gi));
                float sf = 1.f / (1.f + __expf(-gf));
                float so = 1.f / (1.f + __expf(-go));
                float tg = 1.f - 2.f / (__expf(2.f * gg) + 1.f);
                float c  = sf * cs[w][j] + si * tg;
                cs[w][j] = c;
                hs[w][j] = so * (1.f - 2.f / (__expf(2.f * c) + 1.f));
            }
        }
    }
    __syncthreads();
    for (int i = tid; i < A_WORDS * (H2 / 4); i += 256) {
        int w = i >> 5, p = i & 31;
        ((float4*)h_char)[(w0 + w) * 32 + p] = *(float4*)&hs[w][p * 4];
    }
}

// ---------------------------------------------------------------- gather x_fin = [emb_word[sent] | h_char]
__global__ void k_gather(const int* __restrict__ sentence, const float* __restrict__ emb_word,
                         const float* __restrict__ h_char, float* __restrict__ x_fin) {
    int i = blockIdx.x * blockDim.x + threadIdx.x;
    const int total = T_LEN * 96;               // 96 float4 per row (384 floats)
    for (; i < total; i += gridDim.x * blockDim.x) {
        int word = i / 96, s = i % 96;
        float4 v;
        if (s < 64) v = ((const float4*)emb_word)[(size_t)sentence[word] * 64 + s];
        else        v = ((const float4*)h_char)[word * 32 + (s - 64)];
        ((float4*)x_fin)[i] = v;
    }
}

// ---------------------------------------------------------------- pre = x_fin @ Wih_f^T + b_f
// M=8192 N=2048 K=384; 128x128 tile, 8x8 microtile, BK=16
__global__ __launch_bounds__(256) void k_pregemm(const float* __restrict__ A,
                                                 const float* __restrict__ B,
                                                 const float* __restrict__ bias,
                                                 float* __restrict__ Cm) {
    __shared__ float As[16][128];
    __shared__ float Bs[16][128];
    const int tid = threadIdx.x;
    const int M0 = blockIdx.x * 128;
    const int N0 = blockIdx.y * 128;
    const int tx = tid & 15, ty = tid >> 4;

    float acc[8][8];
#pragma unroll
    for (int i = 0; i < 8; ++i)
#pragma unroll
        for (int j = 0; j < 8; ++j) acc[i][j] = 0.f;

    float bcol[8];
#pragma unroll
    for (int j = 0; j < 8; ++j) bcol[j] = bias[N0 + tx * 8 + j];

    const int r  = tid >> 1;
    const int kq = (tid & 1) * 8;

    for (int k0 = 0; k0 < 384; k0 += 16) {
        __syncthreads();
        {
            const float4* A4 = (const float4*)A;
            const float4* B4 = (const float4*)B;
            float4 a0 = A4[(M0 + r) * 96 + (k0 + kq) / 4];
            float4 a1 = A4[(M0 + r) * 96 + (k0 + kq) / 4 + 1];
            float4 b0 = B4[(N0 + r) * 96 + (k0 + kq) / 4];
            float4 b1 = B4[(N0 + r) * 96 + (k0 + kq) / 4 + 1];
            As[kq + 0][r] = a0.x; As[kq + 1][r] = a0.y; As[kq + 2][r] = a0.z; As[kq + 3][r] = a0.w;
            As[kq + 4][r] = a1.x; As[kq + 5][r] = a1.y; As[kq + 6][r] = a1.z; As[kq + 7][r] = a1.w;
            Bs[kq + 0][r] = b0.x; Bs[kq + 1][r] = b0.y; Bs[kq + 2][r] = b0.z; Bs[kq + 3][r] = b0.w;
            Bs[kq + 4][r] = b1.x; Bs[kq + 5][r] = b1.y; Bs[kq + 6][r] = b1.z; Bs[kq + 7][r] = b1.w;
        }
        __syncthreads();
#pragma unroll
        for (int k = 0; k < 16; ++k) {
            float a[8], b[8];
            *(float4*)&a[0] = *(const float4*)&As[k][ty * 8];
            *(float4*)&a[4] = *(const float4*)&As[k][ty * 8 + 4];
            *(float4*)&b[0] = *(const float4*)&Bs[k][tx * 8];
            *(float4*)&b[4] = *(const float4*)&Bs[k][tx * 8 + 4];
#pragma unroll
            for (int i = 0; i < 8; ++i)
#pragma unroll
                for (int j = 0; j < 8; ++j) acc[i][j] += a[i] * b[j];
        }
    }
    const int n_base = N0 + tx * 8;
#pragma unroll
    for (int i = 0; i < 8; ++i) {
        int m = M0 + ty * 8 + i;
        float4 o0 = make_float4(acc[i][0] + bcol[0], acc[i][1] + bcol[1], acc[i][2] + bcol[2], acc[i][3] + bcol[3]);
        float4 o1 = make_float4(acc[i][4] + bcol[4], acc[i][5] + bcol[5], acc[i][6] + bcol[6], acc[i][7] + bcol[7]);
        float4* C4 = (float4*)(Cm + (size_t)m * 2048 + n_base);
        C4[0] = o0; C4[1] = o1;
    }
}

// ---------------------------------------------------------------- recurrent word LSTM (persistent, 16 blocks)
// block b owns h comps [b*32, b*32+32) -> 128 gate rows. thread: il=tid&127 (row), q=tid>>7 (k-quarter)
__global__ __launch_bounds__(THR_REC) void k_rec(const float* __restrict__ pre,
                                                 const float* __restrict__ Whh,
                                                 float* hglob, unsigned int* flags,
                                                 float* __restrict__ h_seq) {
    const int tid = threadIdx.x;
    const int b   = blockIdx.x;
    const int il  = tid & 127;
    const int q   = tid >> 7;                   // wave-uniform
    const int typ = il >> 5, jj = il & 31;
    const int rowg = typ * HID + b * 32 + jj;   // global gate row

    float w[128];
    {
        const float4* W4 = (const float4*)(Whh + (size_t)rowg * HID + q * 128);
#pragma unroll
        for (int i = 0; i < 32; ++i) {
            float4 v = W4[i];
            w[i * 4] = v.x; w[i * 4 + 1] = v.y; w[i * 4 + 2] = v.z; w[i * 4 + 3] = v.w;
        }
    }

    __shared__ float h_lds[512];
    __shared__ float psum[512];
    __shared__ float act[128];
    float c = 0.f;
    const int jglob = b * 32 + (tid & 31);

    for (int step = 0; step < T_LEN; ++step) {
        // prefetch pre row values (overlaps the spin)
        float pre_v = 0.f;
        if (tid < 128)
            pre_v = pre[(size_t)step * 2048 + (tid >> 5) * HID + b * 32 + (tid & 31)];

        // wait: all 16 producer flags >= step  (h_step published)
        if (tid < NBLK_REC) {
            while (__hip_atomic_load(&flags[tid], __ATOMIC_RELAXED, __HIP_MEMORY_SCOPE_AGENT) < (unsigned)step)
                __builtin_amdgcn_s_sleep(1);
        }
        __syncthreads();

        // load h_step (coherent agent-scope reads)
        {
            const float* src = hglob + (step & 1) * HID;
            h_lds[tid] = __hip_atomic_load(&src[tid], __ATOMIC_RELAXED, __HIP_MEMORY_SCOPE_AGENT);
        }
        __syncthreads();

        // quarter-dot: 128 MACs per thread
        float accv = 0.f;
        {
            const float4* h4 = (const float4*)&h_lds[q * 128];
#pragma unroll
            for (int i = 0; i < 32; ++i) {
                float4 hv = h4[i];
                accv += w[i * 4] * hv.x + w[i * 4 + 1] * hv.y + w[i * 4 + 2] * hv.z + w[i * 4 + 3] * hv.w;
            }
        }
        psum[q * 128 + il] = accv;
        __syncthreads();

        if (tid < 128) {
            float g = psum[tid] + psum[128 + tid] + psum[256 + tid] + psum[384 + tid] + pre_v;
            float a;
            if (tid < 64)       a = 1.f / (1.f + __expf(-g));            // i, f
            else if (tid < 96)  a = 1.f - 2.f / (__expf(2.f * g) + 1.f); // tanh(g)
            else                a = 1.f / (1.f + __expf(-g));            // o
            act[tid] = a;
        }
        __syncthreads();

        if (tid < 32) {
            float si = act[tid], sf = act[32 + tid], tg = act[64 + tid], so = act[96 + tid];
            c = sf * c + si * tg;
            float h = so * (1.f - 2.f / (__expf(2.f * c) + 1.f));
            __hip_atomic_store(&hglob[((step + 1) & 1) * HID + jglob], h,
                               __ATOMIC_RELAXED, __HIP_MEMORY_SCOPE_AGENT);
            h_seq[(size_t)step * HID + jglob] = h;
            __threadfence();   // h visible device-wide before flag
        }
        __syncthreads();
        if (tid == 0)
            __hip_atomic_store(&flags[b], (unsigned)(step + 1),
                               __ATOMIC_RELAXED, __HIP_MEMORY_SCOPE_AGENT);
    }
}

// ---------------------------------------------------------------- tags + log_softmax (wave per word, lane = tag)
__global__ __launch_bounds__(256) void k_tag(const float* __restrict__ h_seq,
                                             const float* __restrict__ Wt,
                                             const float* __restrict__ bt,
                                             float* __restrict__ out) {
    const int tid  = threadIdx.x;
    const int lane = tid & 63;
    const int word = blockIdx.x * 4 + (tid >> 6);
    const float4* W4 = (const float4*)Wt;
    const float4* h4 = (const float4*)(h_seq + (size_t)word * HID);
    float acc = bt[lane];
#pragma unroll 8
    for (int k = 0; k < 128; ++k) {
        float4 a = W4[lane * 128 + k];
        float4 h = h4[k];
        acc += a.x * h.x + a.y * h.y + a.z * h.z + a.w * h.w;
    }
    float m = acc;
#pragma unroll
    for (int o = 32; o >= 1; o >>= 1) m = fmaxf(m, __shfl_xor(m, o, 64));
    float e = __expf(acc - m);
    float s = e;
#pragma unroll
    for (int o = 32; o >= 1; o >>= 1) s += __shfl_xor(s, o, 64);
    out[(size_t)word * TAGS + lane] = acc - m - __logf(s);
}

// ---------------------------------------------------------------- launch
extern "C" void kernel_launch(void* const* d_in, const int* in_sizes, int n_in,
                              void* d_out, int out_size, void* d_ws, size_t ws_size,
                              hipStream_t stream) {
    const int*   sentence  = (const int*)d_in[0];
    const int*   seq_chars = (const int*)d_in[1];
    const float* emb_word  = (const float*)d_in[2];
    const float* emb_char  = (const float*)d_in[3];
    const float* Wih_c     = (const float*)d_in[4];
    const float* Whh_c     = (const float*)d_in[5];
    const float* b_c       = (const float*)d_in[6];
    const float* Wih_f     = (const float*)d_in[7];
    const float* Whh_f     = (const float*)d_in[8];
    const float* b_f       = (const float*)d_in[9];
    const float* W_tag     = (const float*)d_in[10];
    const float* b_tag     = (const float*)d_in[11];
    float* out = (float*)d_out;

    float* ws     = (float*)d_ws;
    float* h_char = ws;                                  // 8192*128
    float* x_fin  = h_char + (size_t)T_LEN * H2;         // 8192*384
    float* pre    = x_fin  + (size_t)T_LEN * 384;        // 8192*2048
    float* h_seq  = pre    + (size_t)T_LEN * 2048;       // 8192*512
    float* hglob  = h_seq  + (size_t)T_LEN * HID;        // 2*512
    unsigned int* flags = (unsigned int*)(hglob + 2 * HID);

    hipLaunchKernelGGL(k_init,   dim3(1),              dim3(256), 0, stream, hglob, flags);
    hipLaunchKernelGGL(k_char,   dim3(T_LEN / A_WORDS), dim3(256), 0, stream,
                       seq_chars, emb_char, Wih_c, Whh_c, b_c, h_char);
    hipLaunchKernelGGL(k_gather, dim3(1024),           dim3(256), 0, stream,
                       sentence, emb_word, h_char, x_fin);
    hipLaunchKernelGGL(k_pregemm, dim3(64, 16),        dim3(256), 0, stream,
                       x_fin, Wih_f, b_f, pre);
    hipLaunchKernelGGL(k_rec,    dim3(NBLK_REC),       dim3(THR_REC), 0, stream,
                       pre, Whh_f, hglob, flags, h_seq);
    hipLaunchKernelGGL(k_tag,    dim3(T_LEN / 4),      dim3(256), 0, stream,
                       h_seq, W_tag, b_tag, out);
}

// Round 4
// 18029.494 us; speedup vs baseline: 1.4587x; 1.4587x over previous
//
#include <hip/hip_runtime.h>

#define T_LEN 8192
#define L_CH  16
#define EW    256
#define EC    64
#define HID   512
#define H2    128
#define TAGS  64

#define NBLK_REC 16
#define A_WORDS  16

// ---------------------------------------------------------------- init
// hbuf: 2 slots x 512 packed words (tag<<32 | float_bits).
// slot0 = h(0)=0 with tag 1; slot1 = invalid (0).
__global__ void k_init(unsigned long long* hbuf) {
    int t = threadIdx.x;
    for (int i = t; i < 2 * HID; i += blockDim.x)
        hbuf[i] = (i < HID) ? (1ULL << 32) : 0ULL;
}

// ---------------------------------------------------------------- char LSTM
__global__ __launch_bounds__(256) void k_char(const int* __restrict__ seq_chars,
                                              const float* __restrict__ emb_char,
                                              const float* __restrict__ Wih,
                                              const float* __restrict__ Whh,
                                              const float* __restrict__ bc,
                                              float* __restrict__ h_char) {
    __shared__ float xs[A_WORDS][76];
    __shared__ float hs[A_WORDS][132];
    __shared__ float cs[A_WORDS][128];
    __shared__ float gs[A_WORDS][512];

    const int tid = threadIdx.x;
    const int w0  = blockIdx.x * A_WORDS;

    for (int i = tid; i < A_WORDS * 132; i += 256) hs[i / 132][i % 132] = 0.f;
    for (int i = tid; i < A_WORDS * 128; i += 256) cs[i >> 7][i & 127] = 0.f;

    const int rowg = tid >> 2;
    const int wg   = tid & 3;
    const int r0   = rowg * 8;
    const int wb   = wg * 4;

    float bias_r[8];
#pragma unroll
    for (int r = 0; r < 8; ++r) bias_r[r] = bc[r0 + r];

    for (int l = 0; l < L_CH; ++l) {
        __syncthreads();
        {
            int w = tid >> 4, p = tid & 15;
            int ci = seq_chars[(w0 + w) * L_CH + l];
            float4 v = ((const float4*)emb_char)[ci * 16 + p];
            *(float4*)&xs[w][p * 4] = v;
        }
        __syncthreads();

        float acc[8][4];
#pragma unroll
        for (int r = 0; r < 8; ++r)
#pragma unroll
            for (int w = 0; w < 4; ++w) acc[r][w] = bias_r[r];

#pragma unroll 4
        for (int k4 = 0; k4 < 16; ++k4) {
            float4 wv[8];
#pragma unroll
            for (int r = 0; r < 8; ++r) wv[r] = ((const float4*)Wih)[(r0 + r) * 16 + k4];
#pragma unroll
            for (int w = 0; w < 4; ++w) {
                const float4 xv = *(const float4*)&xs[wb + w][k4 * 4];
#pragma unroll
                for (int r = 0; r < 8; ++r)
                    acc[r][w] += wv[r].x * xv.x + wv[r].y * xv.y + wv[r].z * xv.z + wv[r].w * xv.w;
            }
        }
#pragma unroll 2
        for (int k4 = 0; k4 < 32; ++k4) {
            float4 wv[8];
#pragma unroll
            for (int r = 0; r < 8; ++r) wv[r] = ((const float4*)Whh)[(r0 + r) * 32 + k4];
#pragma unroll
            for (int w = 0; w < 4; ++w) {
                const float4 hv = *(const float4*)&hs[wb + w][k4 * 4];
#pragma unroll
                for (int r = 0; r < 8; ++r)
                    acc[r][w] += wv[r].x * hv.x + wv[r].y * hv.y + wv[r].z * hv.z + wv[r].w * hv.w;
            }
        }
#pragma unroll
        for (int r = 0; r < 8; ++r)
#pragma unroll
            for (int w = 0; w < 4; ++w) gs[wb + w][r0 + r] = acc[r][w];
        __syncthreads();

        {
            int w = tid >> 4;
            int j0 = (tid & 15) * 8;
#pragma unroll
            for (int u = 0; u < 8; ++u) {
                int j = j0 + u;
                float gi = gs[w][j], gf = gs[w][128 + j], gg = gs[w][256 + j], go = gs[w][384 + j];
                float si = 1.f / (1.f + __expf(-gi));
                float sf = 1.f / (1.f + __expf(-gf));
                float so = 1.f / (1.f + __expf(-go));
                float tg = 1.f - 2.f / (__expf(2.f * gg) + 1.f);
                float c  = sf * cs[w][j] + si * tg;
                cs[w][j] = c;
                hs[w][j] = so * (1.f - 2.f / (__expf(2.f * c) + 1.f));
            }
        }
    }
    __syncthreads();
    for (int i = tid; i < A_WORDS * (H2 / 4); i += 256) {
        int w = i >> 5, p = i & 31;
        ((float4*)h_char)[(w0 + w) * 32 + p] = *(float4*)&hs[w][p * 4];
    }
}

// ---------------------------------------------------------------- gather x_fin = [emb_word[sent] | h_char]
__global__ void k_gather(const int* __restrict__ sentence, const float* __restrict__ emb_word,
                         const float* __restrict__ h_char, float* __restrict__ x_fin) {
    int i = blockIdx.x * blockDim.x + threadIdx.x;
    const int total = T_LEN * 96;
    for (; i < total; i += gridDim.x * blockDim.x) {
        int word = i / 96, s = i % 96;
        float4 v;
        if (s < 64) v = ((const float4*)emb_word)[(size_t)sentence[word] * 64 + s];
        else        v = ((const float4*)h_char)[word * 32 + (s - 64)];
        ((float4*)x_fin)[i] = v;
    }
}

// ---------------------------------------------------------------- pre = x_fin @ Wih_f^T + b_f
__global__ __launch_bounds__(256) void k_pregemm(const float* __restrict__ A,
                                                 const float* __restrict__ B,
                                                 const float* __restrict__ bias,
                                                 float* __restrict__ Cm) {
    __shared__ float As[16][128];
    __shared__ float Bs[16][128];
    const int tid = threadIdx.x;
    const int M0 = blockIdx.x * 128;
    const int N0 = blockIdx.y * 128;
    const int tx = tid & 15, ty = tid >> 4;

    float acc[8][8];
#pragma unroll
    for (int i = 0; i < 8; ++i)
#pragma unroll
        for (int j = 0; j < 8; ++j) acc[i][j] = 0.f;

    float bcol[8];
#pragma unroll
    for (int j = 0; j < 8; ++j) bcol[j] = bias[N0 + tx * 8 + j];

    const int r  = tid >> 1;
    const int kq = (tid & 1) * 8;

    for (int k0 = 0; k0 < 384; k0 += 16) {
        __syncthreads();
        {
            const float4* A4 = (const float4*)A;
            const float4* B4 = (const float4*)B;
            float4 a0 = A4[(M0 + r) * 96 + (k0 + kq) / 4];
            float4 a1 = A4[(M0 + r) * 96 + (k0 + kq) / 4 + 1];
            float4 b0 = B4[(N0 + r) * 96 + (k0 + kq) / 4];
            float4 b1 = B4[(N0 + r) * 96 + (k0 + kq) / 4 + 1];
            As[kq + 0][r] = a0.x; As[kq + 1][r] = a0.y; As[kq + 2][r] = a0.z; As[kq + 3][r] = a0.w;
            As[kq + 4][r] = a1.x; As[kq + 5][r] = a1.y; As[kq + 6][r] = a1.z; As[kq + 7][r] = a1.w;
            Bs[kq + 0][r] = b0.x; Bs[kq + 1][r] = b0.y; Bs[kq + 2][r] = b0.z; Bs[kq + 3][r] = b0.w;
            Bs[kq + 4][r] = b1.x; Bs[kq + 5][r] = b1.y; Bs[kq + 6][r] = b1.z; Bs[kq + 7][r] = b1.w;
        }
        __syncthreads();
#pragma unroll
        for (int k = 0; k < 16; ++k) {
            float a[8], b[8];
            *(float4*)&a[0] = *(const float4*)&As[k][ty * 8];
            *(float4*)&a[4] = *(const float4*)&As[k][ty * 8 + 4];
            *(float4*)&b[0] = *(const float4*)&Bs[k][tx * 8];
            *(float4*)&b[4] = *(const float4*)&Bs[k][tx * 8 + 4];
#pragma unroll
            for (int i = 0; i < 8; ++i)
#pragma unroll
                for (int j = 0; j < 8; ++j) acc[i][j] += a[i] * b[j];
        }
    }
    const int n_base = N0 + tx * 8;
#pragma unroll
    for (int i = 0; i < 8; ++i) {
        int m = M0 + ty * 8 + i;
        float4 o0 = make_float4(acc[i][0] + bcol[0], acc[i][1] + bcol[1], acc[i][2] + bcol[2], acc[i][3] + bcol[3]);
        float4 o1 = make_float4(acc[i][4] + bcol[4], acc[i][5] + bcol[5], acc[i][6] + bcol[6], acc[i][7] + bcol[7]);
        float4* C4 = (float4*)(Cm + (size_t)m * 2048 + n_base);
        C4[0] = o0; C4[1] = o1;
    }
}

// ---------------------------------------------------------------- recurrent word LSTM
// 16 persistent blocks x 512 threads. Block b owns h comps [b*32, b*32+32).
// Thread layout: ksl = tid&15 (K-slice of 32), rq = tid>>4 (row quad: rows 4rq..4rq+3).
// Sync: tagged 8B words (tag<<32 | h_bits), 2-slot ring, single poll hop.
__global__ __launch_bounds__(512, 2) void k_rec(const float* __restrict__ pre,
                                                const float* __restrict__ Whh,
                                                unsigned long long* hbuf,
                                                float* __restrict__ h_seq) {
    const int tid = threadIdx.x;
    const int b   = blockIdx.x;
    const int ksl = tid & 15;
    const int rq  = tid >> 4;            // 0..31
    const int typ = rq >> 3;             // 0:i 1:f 2:g 3:o
    const int row_lo = (4 * rq) & 31;    // within 32-row group, 4-aligned
    const int grow0  = typ * HID + b * 32 + row_lo;   // global gate row of j=0

    // weights: rows grow0..grow0+3, cols [ksl*32, ksl*32+32)
    float w[4][32];
#pragma unroll
    for (int j = 0; j < 4; ++j) {
        const float4* Wr = (const float4*)(Whh + (size_t)(grow0 + j) * HID + ksl * 32);
#pragma unroll
        for (int i = 0; i < 8; ++i) {
            float4 v = Wr[i];
            w[j][4 * i] = v.x; w[j][4 * i + 1] = v.y; w[j][4 * i + 2] = v.z; w[j][4 * i + 3] = v.w;
        }
    }

    // padded LDS: h stored as [16][36] (start banks 4*((ksl+i)%8) -> <=2-way)
    __shared__ __align__(16) float h_lds[16 * 36];
    __shared__ __align__(16) float act[128];
    const int st_pos = (tid >> 5) * 36 + (tid & 31);   // store slot for h element 'tid'

    float c = 0.f;
    const int jglob = b * 32 + (tid & 31);             // publisher's h component (tid<32)
    const bool pl = (ksl == 0);

    float4 pre_cur = make_float4(0.f, 0.f, 0.f, 0.f);
    if (pl) pre_cur = *(const float4*)&pre[grow0];

    for (int step = 0; step < T_LEN; ++step) {
        // prefetch next step's pre row (lands during this step's sync+compute)
        float4 pre_nxt = make_float4(0.f, 0.f, 0.f, 0.f);
        if (pl && step + 1 < T_LEN)
            pre_nxt = *(const float4*)&pre[(size_t)(step + 1) * 2048 + grow0];

        // single-hop sync: poll tagged word (tag == step+1 means h(step) ready)
        {
            unsigned long long* wp = &hbuf[(step & 1) * HID + tid];
            const unsigned want = (unsigned)(step + 1);
            unsigned long long vv = __hip_atomic_load(wp, __ATOMIC_RELAXED, __HIP_MEMORY_SCOPE_AGENT);
            while ((unsigned)(vv >> 32) != want) {
                __builtin_amdgcn_s_sleep(1);
                vv = __hip_atomic_load(wp, __ATOMIC_RELAXED, __HIP_MEMORY_SCOPE_AGENT);
            }
            h_lds[st_pos] = __uint_as_float((unsigned)vv);
        }
        __syncthreads();

        // dot: 4 rows x 32-K slice per thread
        float acc0 = 0.f, acc1 = 0.f, acc2 = 0.f, acc3 = 0.f;
        {
            const float* hb = &h_lds[ksl * 36];
#pragma unroll
            for (int i = 0; i < 8; ++i) {
                float4 hv = *(const float4*)(hb + 4 * i);
                acc0 += w[0][4 * i] * hv.x + w[0][4 * i + 1] * hv.y + w[0][4 * i + 2] * hv.z + w[0][4 * i + 3] * hv.w;
                acc1 += w[1][4 * i] * hv.x + w[1][4 * i + 1] * hv.y + w[1][4 * i + 2] * hv.z + w[1][4 * i + 3] * hv.w;
                acc2 += w[2][4 * i] * hv.x + w[2][4 * i + 1] * hv.y + w[2][4 * i + 2] * hv.z + w[2][4 * i + 3] * hv.w;
                acc3 += w[3][4 * i] * hv.x + w[3][4 * i + 1] * hv.y + w[3][4 * i + 2] * hv.z + w[3][4 * i + 3] * hv.w;
            }
        }
        // reduce over 16 K-slices (intra-wave, ksl = low 4 bits of tid)
#pragma unroll
        for (int o = 1; o <= 8; o <<= 1) {
            acc0 += __shfl_xor(acc0, o, 64);
            acc1 += __shfl_xor(acc1, o, 64);
            acc2 += __shfl_xor(acc2, o, 64);
            acc3 += __shfl_xor(acc3, o, 64);
        }

        if (pl) {
            float g0 = acc0 + pre_cur.x;
            float g1 = acc1 + pre_cur.y;
            float g2 = acc2 + pre_cur.z;
            float g3 = acc3 + pre_cur.w;
            float4 a;
            if (typ == 2) {   // tanh gate
                a.x = 1.f - 2.f / (__expf(2.f * g0) + 1.f);
                a.y = 1.f - 2.f / (__expf(2.f * g1) + 1.f);
                a.z = 1.f - 2.f / (__expf(2.f * g2) + 1.f);
                a.w = 1.f - 2.f / (__expf(2.f * g3) + 1.f);
            } else {          // sigmoid gates
                a.x = 1.f / (1.f + __expf(-g0));
                a.y = 1.f / (1.f + __expf(-g1));
                a.z = 1.f / (1.f + __expf(-g2));
                a.w = 1.f / (1.f + __expf(-g3));
            }
            *(float4*)&act[4 * rq] = a;
        }
        __syncthreads();

        if (tid < 32) {
            float si = act[tid], sf = act[32 + tid], tg = act[64 + tid], so = act[96 + tid];
            c = sf * c + si * tg;
            float h = so * (1.f - 2.f / (__expf(2.f * c) + 1.f));
            h_seq[(size_t)step * HID + jglob] = h;
            unsigned long long pack = (((unsigned long long)(unsigned)(step + 2)) << 32)
                                      | (unsigned long long)__float_as_uint(h);
            __hip_atomic_store(&hbuf[((step + 1) & 1) * HID + jglob], pack,
                               __ATOMIC_RELAXED, __HIP_MEMORY_SCOPE_AGENT);
        }
        pre_cur = pre_nxt;
    }
}

// ---------------------------------------------------------------- tags + log_softmax
__global__ __launch_bounds__(256) void k_tag(const float* __restrict__ h_seq,
                                             const float* __restrict__ Wt,
                                             const float* __restrict__ bt,
                                             float* __restrict__ out) {
    const int tid  = threadIdx.x;
    const int lane = tid & 63;
    const int word = blockIdx.x * 4 + (tid >> 6);
    const float4* W4 = (const float4*)Wt;
    const float4* h4 = (const float4*)(h_seq + (size_t)word * HID);
    float acc = bt[lane];
#pragma unroll 8
    for (int k = 0; k < 128; ++k) {
        float4 a = W4[lane * 128 + k];
        float4 h = h4[k];
        acc += a.x * h.x + a.y * h.y + a.z * h.z + a.w * h.w;
    }
    float m = acc;
#pragma unroll
    for (int o = 32; o >= 1; o >>= 1) m = fmaxf(m, __shfl_xor(m, o, 64));
    float e = __expf(acc - m);
    float s = e;
#pragma unroll
    for (int o = 32; o >= 1; o >>= 1) s += __shfl_xor(s, o, 64);
    out[(size_t)word * TAGS + lane] = acc - m - __logf(s);
}

// ---------------------------------------------------------------- launch
extern "C" void kernel_launch(void* const* d_in, const int* in_sizes, int n_in,
                              void* d_out, int out_size, void* d_ws, size_t ws_size,
                              hipStream_t stream) {
    const int*   sentence  = (const int*)d_in[0];
    const int*   seq_chars = (const int*)d_in[1];
    const float* emb_word  = (const float*)d_in[2];
    const float* emb_char  = (const float*)d_in[3];
    const float* Wih_c     = (const float*)d_in[4];
    const float* Whh_c     = (const float*)d_in[5];
    const float* b_c       = (const float*)d_in[6];
    const float* Wih_f     = (const float*)d_in[7];
    const float* Whh_f     = (const float*)d_in[8];
    const float* b_f       = (const float*)d_in[9];
    const float* W_tag     = (const float*)d_in[10];
    const float* b_tag     = (const float*)d_in[11];
    float* out = (float*)d_out;

    float* ws     = (float*)d_ws;
    float* h_char = ws;                                  // 8192*128
    float* x_fin  = h_char + (size_t)T_LEN * H2;         // 8192*384
    float* pre    = x_fin  + (size_t)T_LEN * 384;        // 8192*2048
    float* h_seq  = pre    + (size_t)T_LEN * 2048;       // 8192*512
    unsigned long long* hbuf = (unsigned long long*)(h_seq + (size_t)T_LEN * HID);  // 2*512 x 8B

    hipLaunchKernelGGL(k_init,   dim3(1),               dim3(256), 0, stream, hbuf);
    hipLaunchKernelGGL(k_char,   dim3(T_LEN / A_WORDS), dim3(256), 0, stream,
                       seq_chars, emb_char, Wih_c, Whh_c, b_c, h_char);
    hipLaunchKernelGGL(k_gather, dim3(1024),            dim3(256), 0, stream,
                       sentence, emb_word, h_char, x_fin);
    hipLaunchKernelGGL(k_pregemm, dim3(64, 16),         dim3(256), 0, stream,
                       x_fin, Wih_f, b_f, pre);
    hipLaunchKernelGGL(k_rec,    dim3(NBLK_REC),        dim3(512), 0, stream,
                       pre, Whh_f, hbuf, h_seq);
    hipLaunchKernelGGL(k_tag,    dim3(T_LEN / 4),       dim3(256), 0, stream,
                       h_seq, W_tag, b_tag, out);
}

// Round 9
// 17409.029 us; speedup vs baseline: 1.5107x; 1.0356x over previous
//
#include <hip/hip_runtime.h>

#define T_LEN 8192
#define L_CH  16
#define EW    256
#define EC    64
#define HID   512
#define H2    128
#define TAGS  64

#define NBLK_REC 16
#define A_WORDS  16

// ---------------------------------------------------------------- init
// hbuf: 2 slots x 512 packed words (tag<<32 | float_bits).
// slot0 = h(0)=0 with tag 1; slot1 = invalid (0).
__global__ void k_init(unsigned long long* hbuf) {
    int t = threadIdx.x;
    for (int i = t; i < 2 * HID; i += blockDim.x)
        hbuf[i] = (i < HID) ? (1ULL << 32) : 0ULL;
}

// ---------------------------------------------------------------- char LSTM
__global__ __launch_bounds__(256) void k_char(const int* __restrict__ seq_chars,
                                              const float* __restrict__ emb_char,
                                              const float* __restrict__ Wih,
                                              const float* __restrict__ Whh,
                                              const float* __restrict__ bc,
                                              float* __restrict__ h_char) {
    __shared__ float xs[A_WORDS][76];
    __shared__ float hs[A_WORDS][132];
    __shared__ float cs[A_WORDS][128];
    __shared__ float gs[A_WORDS][512];

    const int tid = threadIdx.x;
    const int w0  = blockIdx.x * A_WORDS;

    for (int i = tid; i < A_WORDS * 132; i += 256) hs[i / 132][i % 132] = 0.f;
    for (int i = tid; i < A_WORDS * 128; i += 256) cs[i >> 7][i & 127] = 0.f;

    const int rowg = tid >> 2;
    const int wg   = tid & 3;
    const int r0   = rowg * 8;
    const int wb   = wg * 4;

    float bias_r[8];
#pragma unroll
    for (int r = 0; r < 8; ++r) bias_r[r] = bc[r0 + r];

    for (int l = 0; l < L_CH; ++l) {
        __syncthreads();
        {
            int w = tid >> 4, p = tid & 15;
            int ci = seq_chars[(w0 + w) * L_CH + l];
            float4 v = ((const float4*)emb_char)[ci * 16 + p];
            *(float4*)&xs[w][p * 4] = v;
        }
        __syncthreads();

        float acc[8][4];
#pragma unroll
        for (int r = 0; r < 8; ++r)
#pragma unroll
            for (int w = 0; w < 4; ++w) acc[r][w] = bias_r[r];

#pragma unroll 4
        for (int k4 = 0; k4 < 16; ++k4) {
            float4 wv[8];
#pragma unroll
            for (int r = 0; r < 8; ++r) wv[r] = ((const float4*)Wih)[(r0 + r) * 16 + k4];
#pragma unroll
            for (int w = 0; w < 4; ++w) {
                const float4 xv = *(const float4*)&xs[wb + w][k4 * 4];
#pragma unroll
                for (int r = 0; r < 8; ++r)
                    acc[r][w] += wv[r].x * xv.x + wv[r].y * xv.y + wv[r].z * xv.z + wv[r].w * xv.w;
            }
        }
#pragma unroll 2
        for (int k4 = 0; k4 < 32; ++k4) {
            float4 wv[8];
#pragma unroll
            for (int r = 0; r < 8; ++r) wv[r] = ((const float4*)Whh)[(r0 + r) * 32 + k4];
#pragma unroll
            for (int w = 0; w < 4; ++w) {
                const float4 hv = *(const float4*)&hs[wb + w][k4 * 4];
#pragma unroll
                for (int r = 0; r < 8; ++r)
                    acc[r][w] += wv[r].x * hv.x + wv[r].y * hv.y + wv[r].z * hv.z + wv[r].w * hv.w;
            }
        }
#pragma unroll
        for (int r = 0; r < 8; ++r)
#pragma unroll
            for (int w = 0; w < 4; ++w) gs[wb + w][r0 + r] = acc[r][w];
        __syncthreads();

        {
            int w = tid >> 4;
            int j0 = (tid & 15) * 8;
#pragma unroll
            for (int u = 0; u < 8; ++u) {
                int j = j0 + u;
                float gi = gs[w][j], gf = gs[w][128 + j], gg = gs[w][256 + j], go = gs[w][384 + j];
                float si = 1.f / (1.f + __expf(-gi));
                float sf = 1.f / (1.f + __expf(-gf));
                float so = 1.f / (1.f + __expf(-go));
                float tg = 1.f - 2.f / (__expf(2.f * gg) + 1.f);
                float c  = sf * cs[w][j] + si * tg;
                cs[w][j] = c;
                hs[w][j] = so * (1.f - 2.f / (__expf(2.f * c) + 1.f));
            }
        }
    }
    __syncthreads();
    for (int i = tid; i < A_WORDS * (H2 / 4); i += 256) {
        int w = i >> 5, p = i & 31;
        ((float4*)h_char)[(w0 + w) * 32 + p] = *(float4*)&hs[w][p * 4];
    }
}

// ---------------------------------------------------------------- gather x_fin = [emb_word[sent] | h_char]
__global__ void k_gather(const int* __restrict__ sentence, const float* __restrict__ emb_word,
                         const float* __restrict__ h_char, float* __restrict__ x_fin) {
    int i = blockIdx.x * blockDim.x + threadIdx.x;
    const int total = T_LEN * 96;
    for (; i < total; i += gridDim.x * blockDim.x) {
        int word = i / 96, s = i % 96;
        float4 v;
        if (s < 64) v = ((const float4*)emb_word)[(size_t)sentence[word] * 64 + s];
        else        v = ((const float4*)h_char)[word * 32 + (s - 64)];
        ((float4*)x_fin)[i] = v;
    }
}

// ---------------------------------------------------------------- pre = x_fin @ Wih_f^T + b_f
__global__ __launch_bounds__(256) void k_pregemm(const float* __restrict__ A,
                                                 const float* __restrict__ B,
                                                 const float* __restrict__ bias,
                                                 float* __restrict__ Cm) {
    __shared__ float As[16][128];
    __shared__ float Bs[16][128];
    const int tid = threadIdx.x;
    const int M0 = blockIdx.x * 128;
    const int N0 = blockIdx.y * 128;
    const int tx = tid & 15, ty = tid >> 4;

    float acc[8][8];
#pragma unroll
    for (int i = 0; i < 8; ++i)
#pragma unroll
        for (int j = 0; j < 8; ++j) acc[i][j] = 0.f;

    float bcol[8];
#pragma unroll
    for (int j = 0; j < 8; ++j) bcol[j] = bias[N0 + tx * 8 + j];

    const int r  = tid >> 1;
    const int kq = (tid & 1) * 8;

    for (int k0 = 0; k0 < 384; k0 += 16) {
        __syncthreads();
        {
            const float4* A4 = (const float4*)A;
            const float4* B4 = (const float4*)B;
            float4 a0 = A4[(M0 + r) * 96 + (k0 + kq) / 4];
            float4 a1 = A4[(M0 + r) * 96 + (k0 + kq) / 4 + 1];
            float4 b0 = B4[(N0 + r) * 96 + (k0 + kq) / 4];
            float4 b1 = B4[(N0 + r) * 96 + (k0 + kq) / 4 + 1];
            As[kq + 0][r] = a0.x; As[kq + 1][r] = a0.y; As[kq + 2][r] = a0.z; As[kq + 3][r] = a0.w;
            As[kq + 4][r] = a1.x; As[kq + 5][r] = a1.y; As[kq + 6][r] = a1.z; As[kq + 7][r] = a1.w;
            Bs[kq + 0][r] = b0.x; Bs[kq + 1][r] = b0.y; Bs[kq + 2][r] = b0.z; Bs[kq + 3][r] = b0.w;
            Bs[kq + 4][r] = b1.x; Bs[kq + 5][r] = b1.y; Bs[kq + 6][r] = b1.z; Bs[kq + 7][r] = b1.w;
        }
        __syncthreads();
#pragma unroll
        for (int k = 0; k < 16; ++k) {
            float a[8], b[8];
            *(float4*)&a[0] = *(const float4*)&As[k][ty * 8];
            *(float4*)&a[4] = *(const float4*)&As[k][ty * 8 + 4];
            *(float4*)&b[0] = *(const float4*)&Bs[k][tx * 8];
            *(float4*)&b[4] = *(const float4*)&Bs[k][tx * 8 + 4];
#pragma unroll
            for (int i = 0; i < 8; ++i)
#pragma unroll
                for (int j = 0; j < 8; ++j) acc[i][j] += a[i] * b[j];
        }
    }
    const int n_base = N0 + tx * 8;
#pragma unroll
    for (int i = 0; i < 8; ++i) {
        int m = M0 + ty * 8 + i;
        float4 o0 = make_float4(acc[i][0] + bcol[0], acc[i][1] + bcol[1], acc[i][2] + bcol[2], acc[i][3] + bcol[3]);
        float4 o1 = make_float4(acc[i][4] + bcol[4], acc[i][5] + bcol[5], acc[i][6] + bcol[6], acc[i][7] + bcol[7]);
        float4* C4 = (float4*)(Cm + (size_t)m * 2048 + n_base);
        C4[0] = o0; C4[1] = o1;
    }
}

// ---------------------------------------------------------------- recurrent word LSTM
// 16 persistent blocks x 1024 threads. Block b owns h comps [b*32, b*32+32).
// Thread: ksl = tid&15 (32-wide K-slice), rp = tid>>4 (row PAIR: gate rows 2rp, 2rp+1).
// 64 weights/thread -> register-resident under __launch_bounds__(1024,4) (128-VGPR budget).
// Sync: tagged 8B words (tag<<32 | h_bits), 2-slot ring, single poll hop.
__global__ __launch_bounds__(1024, 4) void k_rec(const float* __restrict__ pre,
                                                 const float* __restrict__ Whh,
                                                 unsigned long long* hbuf,
                                                 float* __restrict__ h_seq) {
    const int tid = threadIdx.x;
    const int b   = blockIdx.x;
    const int ksl = tid & 15;
    const int rp  = tid >> 4;            // 0..63
    const int typ = rp >> 4;             // 0:i 1:f 2:g 3:o
    const int jj0 = (2 * rp) & 31;       // even, within 32-row group
    const int grow0 = typ * HID + b * 32 + jj0;   // global gate row (even)

    // weights: rows grow0, grow0+1, cols [ksl*32, ksl*32+32)
    float w0[32], w1[32];
    {
        const float4* Wr0 = (const float4*)(Whh + (size_t)grow0 * HID + ksl * 32);
        const float4* Wr1 = (const float4*)(Whh + (size_t)(grow0 + 1) * HID + ksl * 32);
#pragma unroll
        for (int i = 0; i < 8; ++i) {
            float4 v0 = Wr0[i];
            w0[4 * i] = v0.x; w0[4 * i + 1] = v0.y; w0[4 * i + 2] = v0.z; w0[4 * i + 3] = v0.w;
            float4 v1 = Wr1[i];
            w1[4 * i] = v1.x; w1[4 * i + 1] = v1.y; w1[4 * i + 2] = v1.z; w1[4 * i + 3] = v1.w;
        }
    }
    // pin weights in VGPRs: opaque redefinition forbids rematerializing the loads
#pragma unroll
    for (int i = 0; i < 32; ++i)
        asm volatile("" : "+v"(w0[i]), "+v"(w1[i]));

    // padded LDS: h stored as [16][36]
    __shared__ __align__(16) float h_lds[16 * 36];
    __shared__ __align__(16) float act[128];
    const int st_pos = (tid >> 5) * 36 + (tid & 31);   // store slot for h element 'tid' (tid<512)

    float c = 0.f;
    const int jglob = b * 32 + (tid & 31);             // publisher's h component (tid<32)
    const bool pl = (ksl == 0);

    float2 pre_cur = make_float2(0.f, 0.f);
    if (pl) pre_cur = *(const float2*)&pre[grow0];

    for (int step = 0; step < T_LEN; ++step) {
        // prefetch next step's pre rows (lands during this step's sync+compute)
        float2 pre_nxt = make_float2(0.f, 0.f);
        if (pl && step + 1 < T_LEN)
            pre_nxt = *(const float2*)&pre[(size_t)(step + 1) * 2048 + grow0];

        // single-hop sync: poll tagged word (tag == step+1 means h(step) ready)
        if (tid < 512) {
            unsigned long long* wp = &hbuf[(step & 1) * HID + tid];
            const unsigned want = (unsigned)(step + 1);
            unsigned long long vv = __hip_atomic_load(wp, __ATOMIC_RELAXED, __HIP_MEMORY_SCOPE_AGENT);
            while ((unsigned)(vv >> 32) != want) {
                __builtin_amdgcn_s_sleep(1);
                vv = __hip_atomic_load(wp, __ATOMIC_RELAXED, __HIP_MEMORY_SCOPE_AGENT);
            }
            h_lds[st_pos] = __uint_as_float((unsigned)vv);
        }
        __syncthreads();

        // dot: 2 rows x 32-K slice per thread
        float acc0 = 0.f, acc1 = 0.f;
        {
            const float* hb = &h_lds[ksl * 36];
#pragma unroll
            for (int i = 0; i < 8; ++i) {
                float4 hv = *(const float4*)(hb + 4 * i);
                acc0 += w0[4 * i] * hv.x + w0[4 * i + 1] * hv.y + w0[4 * i + 2] * hv.z + w0[4 * i + 3] * hv.w;
                acc1 += w1[4 * i] * hv.x + w1[4 * i + 1] * hv.y + w1[4 * i + 2] * hv.z + w1[4 * i + 3] * hv.w;
            }
        }
        // reduce over 16 K-slices (intra-wave: ksl = low 4 bits of lane)
#pragma unroll
        for (int o = 1; o <= 8; o <<= 1) {
            acc0 += __shfl_xor(acc0, o, 64);
            acc1 += __shfl_xor(acc1, o, 64);
        }

        if (pl) {
            float g0 = acc0 + pre_cur.x;
            float g1 = acc1 + pre_cur.y;
            float2 a;
            if (typ == 2) {   // tanh gate
                a.x = 1.f - 2.f / (__expf(2.f * g0) + 1.f);
                a.y = 1.f - 2.f / (__expf(2.f * g1) + 1.f);
            } else {          // sigmoid gates
                a.x = 1.f / (1.f + __expf(-g0));
                a.y = 1.f / (1.f + __expf(-g1));
            }
            *(float2*)&act[2 * rp] = a;
        }
        __syncthreads();

        if (tid < 32) {
            float si = act[tid], sf = act[32 + tid], tg = act[64 + tid], so = act[96 + tid];
            c = sf * c + si * tg;
            float h = so * (1.f - 2.f / (__expf(2.f * c) + 1.f));
            unsigned long long pack = (((unsigned long long)(unsigned)(step + 2)) << 32)
                                      | (unsigned long long)__float_as_uint(h);
            __hip_atomic_store(&hbuf[((step + 1) & 1) * HID + jglob], pack,
                               __ATOMIC_RELAXED, __HIP_MEMORY_SCOPE_AGENT);
            h_seq[(size_t)step * HID + jglob] = h;
        }
        pre_cur = pre_nxt;
    }
}

// ---------------------------------------------------------------- tags + log_softmax
__global__ __launch_bounds__(256) void k_tag(const float* __restrict__ h_seq,
                                             const float* __restrict__ Wt,
                                             const float* __restrict__ bt,
                                             float* __restrict__ out) {
    const int tid  = threadIdx.x;
    const int lane = tid & 63;
    const int word = blockIdx.x * 4 + (tid >> 6);
    const float4* W4 = (const float4*)Wt;
    const float4* h4 = (const float4*)(h_seq + (size_t)word * HID);
    float acc = bt[lane];
#pragma unroll 8
    for (int k = 0; k < 128; ++k) {
        float4 a = W4[lane * 128 + k];
        float4 h = h4[k];
        acc += a.x * h.x + a.y * h.y + a.z * h.z + a.w * h.w;
    }
    float m = acc;
#pragma unroll
    for (int o = 32; o >= 1; o >>= 1) m = fmaxf(m, __shfl_xor(m, o, 64));
    float e = __expf(acc - m);
    float s = e;
#pragma unroll
    for (int o = 32; o >= 1; o >>= 1) s += __shfl_xor(s, o, 64);
    out[(size_t)word * TAGS + lane] = acc - m - __logf(s);
}

// ---------------------------------------------------------------- launch
extern "C" void kernel_launch(void* const* d_in, const int* in_sizes, int n_in,
                              void* d_out, int out_size, void* d_ws, size_t ws_size,
                              hipStream_t stream) {
    const int*   sentence  = (const int*)d_in[0];
    const int*   seq_chars = (const int*)d_in[1];
    const float* emb_word  = (const float*)d_in[2];
    const float* emb_char  = (const float*)d_in[3];
    const float* Wih_c     = (const float*)d_in[4];
    const float* Whh_c     = (const float*)d_in[5];
    const float* b_c       = (const float*)d_in[6];
    const float* Wih_f     = (const float*)d_in[7];
    const float* Whh_f     = (const float*)d_in[8];
    const float* b_f       = (const float*)d_in[9];
    const float* W_tag     = (const float*)d_in[10];
    const float* b_tag     = (const float*)d_in[11];
    float* out = (float*)d_out;

    float* ws     = (float*)d_ws;
    float* h_char = ws;                                  // 8192*128
    float* x_fin  = h_char + (size_t)T_LEN * H2;         // 8192*384
    float* pre    = x_fin  + (size_t)T_LEN * 384;        // 8192*2048
    float* h_seq  = pre    + (size_t)T_LEN * 2048;       // 8192*512
    unsigned long long* hbuf = (unsigned long long*)(h_seq + (size_t)T_LEN * HID);  // 2*512 x 8B

    hipLaunchKernelGGL(k_init,   dim3(1),               dim3(256), 0, stream, hbuf);
    hipLaunchKernelGGL(k_char,   dim3(T_LEN / A_WORDS), dim3(256), 0, stream,
                       seq_chars, emb_char, Wih_c, Whh_c, b_c, h_char);
    hipLaunchKernelGGL(k_gather, dim3(1024),            dim3(256), 0, stream,
                       sentence, emb_word, h_char, x_fin);
    hipLaunchKernelGGL(k_pregemm, dim3(64, 16),         dim3(256), 0, stream,
                       x_fin, Wih_f, b_f, pre);
    hipLaunchKernelGGL(k_rec,    dim3(NBLK_REC),        dim3(1024), 0, stream,
                       pre, Whh_f, hbuf, h_seq);
    hipLaunchKernelGGL(k_tag,    dim3(T_LEN / 4),       dim3(256), 0, stream,
                       h_seq, W_tag, b_tag, out);
}

// Round 12
// 17092.509 us; speedup vs baseline: 1.5386x; 1.0185x over previous
//
#include <hip/hip_runtime.h>

#define T_LEN 8192
#define L_CH  16
#define EW    256
#define EC    64
#define HID   512
#define H2    128
#define TAGS  64

#define NBLK_REC 16
#define A_WORDS  16

// ---------------------------------------------------------------- init
// hbuf: 2 slots x 512 packed words (tag<<32 | float_bits).
// slot0 = h(0)=0 with tag 1; slot1 = invalid (0).
__global__ void k_init(unsigned long long* hbuf) {
    int t = threadIdx.x;
    for (int i = t; i < 2 * HID; i += blockDim.x)
        hbuf[i] = (i < HID) ? (1ULL << 32) : 0ULL;
}

// ---------------------------------------------------------------- char LSTM
__global__ __launch_bounds__(256) void k_char(const int* __restrict__ seq_chars,
                                              const float* __restrict__ emb_char,
                                              const float* __restrict__ Wih,
                                              const float* __restrict__ Whh,
                                              const float* __restrict__ bc,
                                              float* __restrict__ h_char) {
    __shared__ float xs[A_WORDS][76];
    __shared__ float hs[A_WORDS][132];
    __shared__ float cs[A_WORDS][128];
    __shared__ float gs[A_WORDS][512];

    const int tid = threadIdx.x;
    const int w0  = blockIdx.x * A_WORDS;

    for (int i = tid; i < A_WORDS * 132; i += 256) hs[i / 132][i % 132] = 0.f;
    for (int i = tid; i < A_WORDS * 128; i += 256) cs[i >> 7][i & 127] = 0.f;

    const int rowg = tid >> 2;
    const int wg   = tid & 3;
    const int r0   = rowg * 8;
    const int wb   = wg * 4;

    float bias_r[8];
#pragma unroll
    for (int r = 0; r < 8; ++r) bias_r[r] = bc[r0 + r];

    for (int l = 0; l < L_CH; ++l) {
        __syncthreads();
        {
            int w = tid >> 4, p = tid & 15;
            int ci = seq_chars[(w0 + w) * L_CH + l];
            float4 v = ((const float4*)emb_char)[ci * 16 + p];
            *(float4*)&xs[w][p * 4] = v;
        }
        __syncthreads();

        float acc[8][4];
#pragma unroll
    for (int r = 0; r < 8; ++r)
#pragma unroll
            for (int w = 0; w < 4; ++w) acc[r][w] = bias_r[r];

#pragma unroll 4
        for (int k4 = 0; k4 < 16; ++k4) {
            float4 wv[8];
#pragma unroll
            for (int r = 0; r < 8; ++r) wv[r] = ((const float4*)Wih)[(r0 + r) * 16 + k4];
#pragma unroll
            for (int w = 0; w < 4; ++w) {
                const float4 xv = *(const float4*)&xs[wb + w][k4 * 4];
#pragma unroll
                for (int r = 0; r < 8; ++r)
                    acc[r][w] += wv[r].x * xv.x + wv[r].y * xv.y + wv[r].z * xv.z + wv[r].w * xv.w;
            }
        }
#pragma unroll 2
        for (int k4 = 0; k4 < 32; ++k4) {
            float4 wv[8];
#pragma unroll
            for (int r = 0; r < 8; ++r) wv[r] = ((const float4*)Whh)[(r0 + r) * 32 + k4];
#pragma unroll
            for (int w = 0; w < 4; ++w) {
                const float4 hv = *(const float4*)&hs[wb + w][k4 * 4];
#pragma unroll
                for (int r = 0; r < 8; ++r)
                    acc[r][w] += wv[r].x * hv.x + wv[r].y * hv.y + wv[r].z * hv.z + wv[r].w * hv.w;
            }
        }
#pragma unroll
        for (int r = 0; r < 8; ++r)
#pragma unroll
            for (int w = 0; w < 4; ++w) gs[wb + w][r0 + r] = acc[r][w];
        __syncthreads();

        {
            int w = tid >> 4;
            int j0 = (tid & 15) * 8;
#pragma unroll
            for (int u = 0; u < 8; ++u) {
                int j = j0 + u;
                float gi = gs[w][j], gf = gs[w][128 + j], gg = gs[w][256 + j], go = gs[w][384 + j];
                float si = 1.f / (1.f + __expf(-gi));
                float sf = 1.f / (1.f + __expf(-gf));
                float so = 1.f / (1.f + __expf(-go));
                float tg = 1.f - 2.f / (__expf(2.f * gg) + 1.f);
                float c  = sf * cs[w][j] + si * tg;
                cs[w][j] = c;
                hs[w][j] = so * (1.f - 2.f / (__expf(2.f * c) + 1.f));
            }
        }
    }
    __syncthreads();
    for (int i = tid; i < A_WORDS * (H2 / 4); i += 256) {
        int w = i >> 5, p = i & 31;
        ((float4*)h_char)[(w0 + w) * 32 + p] = *(float4*)&hs[w][p * 4];
    }
}

// ---------------------------------------------------------------- gather x_fin = [emb_word[sent] | h_char]
__global__ void k_gather(const int* __restrict__ sentence, const float* __restrict__ emb_word,
                         const float* __restrict__ h_char, float* __restrict__ x_fin) {
    int i = blockIdx.x * blockDim.x + threadIdx.x;
    const int total = T_LEN * 96;
    for (; i < total; i += gridDim.x * blockDim.x) {
        int word = i / 96, s = i % 96;
        float4 v;
        if (s < 64) v = ((const float4*)emb_word)[(size_t)sentence[word] * 64 + s];
        else        v = ((const float4*)h_char)[word * 32 + (s - 64)];
        ((float4*)x_fin)[i] = v;
    }
}

// ---------------------------------------------------------------- pre = x_fin @ Wih_f^T + b_f
__global__ __launch_bounds__(256) void k_pregemm(const float* __restrict__ A,
                                                 const float* __restrict__ B,
                                                 const float* __restrict__ bias,
                                                 float* __restrict__ Cm) {
    __shared__ float As[16][128];
    __shared__ float Bs[16][128];
    const int tid = threadIdx.x;
    const int M0 = blockIdx.x * 128;
    const int N0 = blockIdx.y * 128;
    const int tx = tid & 15, ty = tid >> 4;

    float acc[8][8];
#pragma unroll
    for (int i = 0; i < 8; ++i)
#pragma unroll
        for (int j = 0; j < 8; ++j) acc[i][j] = 0.f;

    float bcol[8];
#pragma unroll
    for (int j = 0; j < 8; ++j) bcol[j] = bias[N0 + tx * 8 + j];

    const int r  = tid >> 1;
    const int kq = (tid & 1) * 8;

    for (int k0 = 0; k0 < 384; k0 += 16) {
        __syncthreads();
        {
            const float4* A4 = (const float4*)A;
            const float4* B4 = (const float4*)B;
            float4 a0 = A4[(M0 + r) * 96 + (k0 + kq) / 4];
            float4 a1 = A4[(M0 + r) * 96 + (k0 + kq) / 4 + 1];
            float4 b0 = B4[(N0 + r) * 96 + (k0 + kq) / 4];
            float4 b1 = B4[(N0 + r) * 96 + (k0 + kq) / 4 + 1];
            As[kq + 0][r] = a0.x; As[kq + 1][r] = a0.y; As[kq + 2][r] = a0.z; As[kq + 3][r] = a0.w;
            As[kq + 4][r] = a1.x; As[kq + 5][r] = a1.y; As[kq + 6][r] = a1.z; As[kq + 7][r] = a1.w;
            Bs[kq + 0][r] = b0.x; Bs[kq + 1][r] = b0.y; Bs[kq + 2][r] = b0.z; Bs[kq + 3][r] = b0.w;
            Bs[kq + 4][r] = b1.x; Bs[kq + 5][r] = b1.y; Bs[kq + 6][r] = b1.z; Bs[kq + 7][r] = b1.w;
        }
        __syncthreads();
#pragma unroll
        for (int k = 0; k < 16; ++k) {
            float a[8], b[8];
            *(float4*)&a[0] = *(const float4*)&As[k][ty * 8];
            *(float4*)&a[4] = *(const float4*)&As[k][ty * 8 + 4];
            *(float4*)&b[0] = *(const float4*)&Bs[k][tx * 8];
            *(float4*)&b[4] = *(const float4*)&Bs[k][tx * 8 + 4];
#pragma unroll
            for (int i = 0; i < 8; ++i)
#pragma unroll
                for (int j = 0; j < 8; ++j) acc[i][j] += a[i] * b[j];
        }
    }
    const int n_base = N0 + tx * 8;
#pragma unroll
    for (int i = 0; i < 8; ++i) {
        int m = M0 + ty * 8 + i;
        float4 o0 = make_float4(acc[i][0] + bcol[0], acc[i][1] + bcol[1], acc[i][2] + bcol[2], acc[i][3] + bcol[3]);
        float4 o1 = make_float4(acc[i][4] + bcol[4], acc[i][5] + bcol[5], acc[i][6] + bcol[6], acc[i][7] + bcol[7]);
        float4* C4 = (float4*)(Cm + (size_t)m * 2048 + n_base);
        C4[0] = o0; C4[1] = o1;
    }
}

// ---------------------------------------------------------------- recurrent word LSTM
// 16 persistent blocks x 1024 threads. Block b owns h comps [b*32, b*32+32).
// Thread: ksl = tid&15 (32-wide K-slice), rp = tid>>4 (row PAIR: gate rows 2rp, 2rp+1).
// Weights in 16 NAMED float4 SSA values (no arrays -> no alloca -> no scratch; rule #20).
// Sync: tagged 8B words (tag<<32 | h_bits), 2-slot ring, single poll hop.
#define D4(W, H) ((W).x * (H).x + (W).y * (H).y + (W).z * (H).z + (W).w * (H).w)
__global__ __launch_bounds__(1024, 4) void k_rec(const float* __restrict__ pre,
                                                 const float* __restrict__ Whh,
                                                 unsigned long long* hbuf,
                                                 float* __restrict__ h_seq) {
    const int tid = threadIdx.x;
    const int b   = blockIdx.x;
    const int ksl = tid & 15;
    const int rp  = tid >> 4;            // 0..63
    const int typ = rp >> 4;             // 0:i 1:f 2:g 3:o
    const int jj0 = (2 * rp) & 31;       // even, within 32-row group
    const int grow0 = typ * HID + b * 32 + jj0;   // global gate row (even)

    // weights: rows grow0, grow0+1, cols [ksl*32, ksl*32+32) — 16 named float4 values
    const float4* Wr0 = (const float4*)(Whh + (size_t)grow0 * HID + ksl * 32);
    const float4* Wr1 = (const float4*)(Whh + (size_t)(grow0 + 1) * HID + ksl * 32);
    const float4 wa0 = Wr0[0], wa1 = Wr0[1], wa2 = Wr0[2], wa3 = Wr0[3];
    const float4 wa4 = Wr0[4], wa5 = Wr0[5], wa6 = Wr0[6], wa7 = Wr0[7];
    const float4 wb0 = Wr1[0], wb1 = Wr1[1], wb2 = Wr1[2], wb3 = Wr1[3];
    const float4 wb4 = Wr1[4], wb5 = Wr1[5], wb6 = Wr1[6], wb7 = Wr1[7];

    // padded LDS: h stored as [16][36]
    __shared__ __align__(16) float h_lds[16 * 36];
    __shared__ __align__(16) float act[128];
    const int st_pos = (tid >> 5) * 36 + (tid & 31);   // store slot for h element 'tid' (tid<512)

    float c = 0.f;
    const int jglob = b * 32 + (tid & 31);             // publisher's h component (tid<32)
    const bool pl = (ksl == 0);

    float2 pre_cur = make_float2(0.f, 0.f);
    if (pl) pre_cur = *(const float2*)&pre[grow0];

    for (int step = 0; step < T_LEN; ++step) {
        // prefetch next step's pre rows (lands during this step's sync+compute)
        float2 pre_nxt = make_float2(0.f, 0.f);
        if (pl && step + 1 < T_LEN)
            pre_nxt = *(const float2*)&pre[(size_t)(step + 1) * 2048 + grow0];

        // single-hop sync: poll tagged word (tag == step+1 means h(step) ready)
        if (tid < 512) {
            unsigned long long* wp = &hbuf[(step & 1) * HID + tid];
            const unsigned want = (unsigned)(step + 1);
            unsigned long long vv = __hip_atomic_load(wp, __ATOMIC_RELAXED, __HIP_MEMORY_SCOPE_AGENT);
            while ((unsigned)(vv >> 32) != want) {
                __builtin_amdgcn_s_sleep(1);
                vv = __hip_atomic_load(wp, __ATOMIC_RELAXED, __HIP_MEMORY_SCOPE_AGENT);
            }
            h_lds[st_pos] = __uint_as_float((unsigned)vv);
        }
        __syncthreads();

        // dot: 2 rows x 32-K slice per thread, all named SSA values
        float acc0, acc1;
        {
            const float4* h4 = (const float4*)&h_lds[ksl * 36];
            const float4 h0 = h4[0], h1 = h4[1], h2 = h4[2], h3 = h4[3];
            const float4 h4v = h4[4], h5 = h4[5], h6 = h4[6], h7 = h4[7];
            acc0 = D4(wa0, h0) + D4(wa1, h1) + D4(wa2, h2) + D4(wa3, h3)
                 + D4(wa4, h4v) + D4(wa5, h5) + D4(wa6, h6) + D4(wa7, h7);
            acc1 = D4(wb0, h0) + D4(wb1, h1) + D4(wb2, h2) + D4(wb3, h3)
                 + D4(wb4, h4v) + D4(wb5, h5) + D4(wb6, h6) + D4(wb7, h7);
        }
        // reduce over 16 K-slices (intra-wave: ksl = low 4 bits of lane)
#pragma unroll
        for (int o = 1; o <= 8; o <<= 1) {
            acc0 += __shfl_xor(acc0, o, 64);
            acc1 += __shfl_xor(acc1, o, 64);
        }

        if (pl) {
            float g0 = acc0 + pre_cur.x;
            float g1 = acc1 + pre_cur.y;
            float2 a;
            if (typ == 2) {   // tanh gate
                a.x = 1.f - 2.f / (__expf(2.f * g0) + 1.f);
                a.y = 1.f - 2.f / (__expf(2.f * g1) + 1.f);
            } else {          // sigmoid gates
                a.x = 1.f / (1.f + __expf(-g0));
                a.y = 1.f / (1.f + __expf(-g1));
            }
            *(float2*)&act[2 * rp] = a;
        }
        __syncthreads();

        if (tid < 32) {
            float si = act[tid], sf = act[32 + tid], tg = act[64 + tid], so = act[96 + tid];
            c = sf * c + si * tg;
            float h = so * (1.f - 2.f / (__expf(2.f * c) + 1.f));
            unsigned long long pack = (((unsigned long long)(unsigned)(step + 2)) << 32)
                                      | (unsigned long long)__float_as_uint(h);
            __hip_atomic_store(&hbuf[((step + 1) & 1) * HID + jglob], pack,
                               __ATOMIC_RELAXED, __HIP_MEMORY_SCOPE_AGENT);
            h_seq[(size_t)step * HID + jglob] = h;
        }
        pre_cur = pre_nxt;
    }
}

// ---------------------------------------------------------------- tags + log_softmax
__global__ __launch_bounds__(256) void k_tag(const float* __restrict__ h_seq,
                                             const float* __restrict__ Wt,
                                             const float* __restrict__ bt,
                                             float* __restrict__ out) {
    const int tid  = threadIdx.x;
    const int lane = tid & 63;
    const int word = blockIdx.x * 4 + (tid >> 6);
    const float4* W4 = (const float4*)Wt;
    const float4* h4 = (const float4*)(h_seq + (size_t)word * HID);
    float acc = bt[lane];
#pragma unroll 8
    for (int k = 0; k < 128; ++k) {
        float4 a = W4[lane * 128 + k];
        float4 h = h4[k];
        acc += a.x * h.x + a.y * h.y + a.z * h.z + a.w * h.w;
    }
    float m = acc;
#pragma unroll
    for (int o = 32; o >= 1; o >>= 1) m = fmaxf(m, __shfl_xor(m, o, 64));
    float e = __expf(acc - m);
    float s = e;
#pragma unroll
    for (int o = 32; o >= 1; o >>= 1) s += __shfl_xor(s, o, 64);
    out[(size_t)word * TAGS + lane] = acc - m - __logf(s);
}

// ---------------------------------------------------------------- launch
extern "C" void kernel_launch(void* const* d_in, const int* in_sizes, int n_in,
                              void* d_out, int out_size, void* d_ws, size_t ws_size,
                              hipStream_t stream) {
    const int*   sentence  = (const int*)d_in[0];
    const int*   seq_chars = (const int*)d_in[1];
    const float* emb_word  = (const float*)d_in[2];
    const float* emb_char  = (const float*)d_in[3];
    const float* Wih_c     = (const float*)d_in[4];
    const float* Whh_c     = (const float*)d_in[5];
    const float* b_c       = (const float*)d_in[6];
    const float* Wih_f     = (const float*)d_in[7];
    const float* Whh_f     = (const float*)d_in[8];
    const float* b_f       = (const float*)d_in[9];
    const float* W_tag     = (const float*)d_in[10];
    const float* b_tag     = (const float*)d_in[11];
    float* out = (float*)d_out;

    float* ws     = (float*)d_ws;
    float* h_char = ws;                                  // 8192*128
    float* x_fin  = h_char + (size_t)T_LEN * H2;         // 8192*384
    float* pre    = x_fin  + (size_t)T_LEN * 384;        // 8192*2048
    float* h_seq  = pre    + (size_t)T_LEN * 2048;       // 8192*512
    unsigned long long* hbuf = (unsigned long long*)(h_seq + (size_t)T_LEN * HID);  // 2*512 x 8B

    hipLaunchKernelGGL(k_init,   dim3(1),               dim3(256), 0, stream, hbuf);
    hipLaunchKernelGGL(k_char,   dim3(T_LEN / A_WORDS), dim3(256), 0, stream,
                       seq_chars, emb_char, Wih_c, Whh_c, b_c, h_char);
    hipLaunchKernelGGL(k_gather, dim3(1024),            dim3(256), 0, stream,
                       sentence, emb_word, h_char, x_fin);
    hipLaunchKernelGGL(k_pregemm, dim3(64, 16),         dim3(256), 0, stream,
                       x_fin, Wih_f, b_f, pre);
    hipLaunchKernelGGL(k_rec,    dim3(NBLK_REC),        dim3(1024), 0, stream,
                       pre, Whh_f, hbuf, h_seq);
    hipLaunchKernelGGL(k_tag,    dim3(T_LEN / 4),       dim3(256), 0, stream,
                       h_seq, W_tag, b_tag, out);
}